// Round 1
// baseline (353.247 us; speedup 1.0000x reference)
//
#include <hip/hip_runtime.h>
#include <math.h>

#define D_DIM 128
#define A_DIM 128

__device__ __forceinline__ float fast_tanh(float v) {
    // tanh(v) = 1 - 2/(exp(2v)+1); exact at +/-inf, NaN-free for finite v
    float e = __expf(2.0f * v);
    return 1.0f - 2.0f * __builtin_amdgcn_rcpf(e + 1.0f);
}

// K1: scores[i] = sum_a tanh( dot(x_i, W1[:,a]) + b1[a] ) * W2[a]
// (b2 omitted: uniform additive constant cancels in the segment softmax)
extern "C" __global__ void __launch_bounds__(256)
scores_kernel(const float* __restrict__ x,
              const float* __restrict__ W1,
              const float* __restrict__ b1,
              const float* __restrict__ W2,
              float* __restrict__ scores, int N)
{
    __shared__ float sW1[D_DIM * A_DIM];   // 64 KB, [k][a] row-major
    __shared__ float sB1[A_DIM];
    __shared__ float sW2[A_DIM];

    for (int idx = threadIdx.x; idx < (D_DIM * A_DIM) / 4; idx += 256)
        reinterpret_cast<float4*>(sW1)[idx] = reinterpret_cast<const float4*>(W1)[idx];
    if (threadIdx.x < A_DIM) {
        sB1[threadIdx.x] = b1[threadIdx.x];
        sW2[threadIdx.x] = W2[threadIdx.x];
    }
    __syncthreads();

    const int row = blockIdx.x * 256 + threadIdx.x;
    if (row >= N) return;

    // whole x row in registers (128 VGPRs)
    float xreg[D_DIM];
    {
        const float4* xr = reinterpret_cast<const float4*>(x + (size_t)row * D_DIM);
        #pragma unroll
        for (int j = 0; j < D_DIM / 4; ++j) {
            float4 v = xr[j];
            xreg[4*j+0] = v.x; xreg[4*j+1] = v.y;
            xreg[4*j+2] = v.z; xreg[4*j+3] = v.w;
        }
    }

    float s = 0.0f;
    #pragma unroll 1
    for (int a = 0; a < A_DIM; a += 4) {
        float acc0 = sB1[a+0], acc1 = sB1[a+1], acc2 = sB1[a+2], acc3 = sB1[a+3];
        #pragma unroll
        for (int k = 0; k < D_DIM; ++k) {
            // uniform address across the wave -> LDS broadcast, no bank conflict
            float4 w = *reinterpret_cast<const float4*>(&sW1[k * A_DIM + a]);
            float xv = xreg[k];
            acc0 = fmaf(xv, w.x, acc0);
            acc1 = fmaf(xv, w.y, acc1);
            acc2 = fmaf(xv, w.z, acc2);
            acc3 = fmaf(xv, w.w, acc3);
        }
        s = fmaf(fast_tanh(acc0), sW2[a+0], s);
        s = fmaf(fast_tanh(acc1), sW2[a+1], s);
        s = fmaf(fast_tanh(acc2), sW2[a+2], s);
        s = fmaf(fast_tanh(acc3), sW2[a+3], s);
    }
    scores[row] = s;
}

__device__ __forceinline__ int lower_bound_i32(const int* __restrict__ arr, int n, int val) {
    int lo = 0, hi = n;
    while (lo < hi) {
        int mid = (lo + hi) >> 1;
        if (arr[mid] < val) lo = mid + 1; else hi = mid;
    }
    return lo;
}

// K2: per-segment max and sum(exp(s-max)); also record segment bounds
extern "C" __global__ void __launch_bounds__(256)
segstats_kernel(const float* __restrict__ scores, const int* __restrict__ bidx,
                int N, float* __restrict__ seg_max, float* __restrict__ seg_denom,
                int* __restrict__ seg_start)
{
    const int b = blockIdx.x;
    const int lo = lower_bound_i32(bidx, N, b);
    const int hi = lower_bound_i32(bidx, N, b + 1);
    if (threadIdx.x == 0) {
        seg_start[b] = lo;
        if (b == (int)gridDim.x - 1) seg_start[b + 1] = hi;  // == N
    }

    __shared__ float red[256];
    float m = -INFINITY;
    for (int i = lo + threadIdx.x; i < hi; i += 256) m = fmaxf(m, scores[i]);
    red[threadIdx.x] = m;
    __syncthreads();
    #pragma unroll
    for (int off = 128; off > 0; off >>= 1) {
        if (threadIdx.x < off) red[threadIdx.x] = fmaxf(red[threadIdx.x], red[threadIdx.x + off]);
        __syncthreads();
    }
    m = red[0];
    __syncthreads();

    float sum = 0.0f;
    for (int i = lo + threadIdx.x; i < hi; i += 256) sum += __expf(scores[i] - m);
    red[threadIdx.x] = sum;
    __syncthreads();
    #pragma unroll
    for (int off = 128; off > 0; off >>= 1) {
        if (threadIdx.x < off) red[threadIdx.x] += red[threadIdx.x + off];
        __syncthreads();
    }
    if (threadIdx.x == 0) { seg_max[b] = m; seg_denom[b] = red[0]; }
}

// K3: out[b][d] = sum_{i in seg b} (exp(s_i - max_b)/denom_b) * x[i][d]
extern "C" __global__ void __launch_bounds__(128)
weighted_sum_kernel(const float* __restrict__ x, const float* __restrict__ scores,
                    const float* __restrict__ seg_max, const float* __restrict__ seg_denom,
                    const int* __restrict__ seg_start, float* __restrict__ out,
                    int chunks)
{
    const int b = blockIdx.x;
    const int c = blockIdx.y;
    const int lo = seg_start[b], hi = seg_start[b + 1];
    const int len = hi - lo;
    if (len <= 0) return;
    const int per = (len + chunks - 1) / chunks;
    const int s0 = lo + c * per;
    const int s1 = min(hi, s0 + per);
    if (s0 >= s1) return;

    const float m = seg_max[b];
    const float inv_den = 1.0f / seg_denom[b];
    const int d = threadIdx.x;

    float acc = 0.0f;
    #pragma unroll 4
    for (int i = s0; i < s1; ++i) {
        float w = __expf(scores[i] - m) * inv_den;   // scores[i]: uniform -> broadcast
        acc = fmaf(w, x[(size_t)i * D_DIM + d], acc); // coalesced 512B per row
    }
    atomicAdd(&out[b * D_DIM + d], acc);
}

extern "C" void kernel_launch(void* const* d_in, const int* in_sizes, int n_in,
                              void* d_out, int out_size, void* d_ws, size_t ws_size,
                              hipStream_t stream)
{
    const float* x    = (const float*)d_in[0];
    const int*   bidx = (const int*)d_in[1];
    const float* W1   = (const float*)d_in[2];
    const float* b1   = (const float*)d_in[3];
    const float* W2   = (const float*)d_in[4];
    // d_in[5] = b2: cancels in softmax, unused

    const int N = in_sizes[1];
    const int B = out_size / D_DIM;

    float* out = (float*)d_out;
    char* ws = (char*)d_ws;
    float* scores    = (float*)ws;  // N floats
    size_t off = ((size_t)N * sizeof(float) + 255) & ~(size_t)255;
    float* seg_max   = (float*)(ws + off);
    float* seg_denom = seg_max + B;
    int*   seg_start = (int*)(seg_denom + B);  // B+1 ints

    hipMemsetAsync(d_out, 0, (size_t)out_size * sizeof(float), stream);

    const int blocks1 = (N + 255) / 256;
    scores_kernel<<<blocks1, 256, 0, stream>>>(x, W1, b1, W2, scores, N);
    segstats_kernel<<<B, 256, 0, stream>>>(scores, bidx, N, seg_max, seg_denom, seg_start);
    const int chunks = 8;
    weighted_sum_kernel<<<dim3(B, chunks), 128, 0, stream>>>(
        x, scores, seg_max, seg_denom, seg_start, out, chunks);
}